// Round 2
// baseline (592.541 us; speedup 1.0000x reference)
//
#include <hip/hip_runtime.h>
#include <math.h>

// Soft-Viterbi structured decoding: B=32, T=512, N=128, fp32.
// Linear-space formulation, ONE barrier + ONE LDS round trip per step.
//
// Round-2 restructure: register-blocked dot products. Each lane owns
// 4 contiguous states (quad q = lane>>3) and a 16-element K-chunk
// (kc = lane&7), so per step it issues only 4 ds_read_b128 (granules
// kc, kc+8, kc+16, kc+24 -> banks 4kc..4kc+3: all 32 banks covered once,
// 8-lane broadcast, ZERO bank conflicts) and does 4x16 FMAs.
// LDS return traffic drops 4x (64KB -> 16KB per block-step); the old
// layout's 2-address/same-bank pattern (4 conflict cyc per b128) is gone.
// Partial sums combine via 3 shfl_xor rounds within the 8-lane group.
//
// Forward:  alpha~_t = d_t * r_{t-1} * Z_raw,t ;  Z_raw,t[n] = sum_p T[p,n] alpha~_{t-1}[p]
//           d_t = exp(em_t) (prefetched, off-chain), r_{t-1} = 1/alpha~_{t-1}[0]
//           alpha~_t stashed into out[b][t] (scratch-in-output), r_t in LDS sarr[].
// Backward: p_t[m] = alpha~_t[m] * sum_n q[n] T[m,n],
//           q[n] = p_{t+1}[n] * d_{t+1}[n] * r_t / alpha~_{t+1}[n]  (prefetched off-chain).

#define TT 512
#define BB 32
#define NN 128
#define EPSC 1e-10f
#define TINY 1e-33f

// Raw workgroup barrier with LDS-only drain (global ops stay in flight).
__device__ __forceinline__ void bar_lds() {
  __builtin_amdgcn_sched_barrier(0);
  asm volatile("s_waitcnt lgkmcnt(0)" ::: "memory");
  __builtin_amdgcn_s_barrier();
  __builtin_amdgcn_sched_barrier(0);
}

// 4-state x 16-element partial dot + 8-lane combine. All 8 lanes of the
// quad end with the full 128-length sums in z[0..3].
__device__ __forceinline__ void dot16(const float4 av[4], const float tm[4][16], float z[4]) {
  #pragma unroll
  for (int s = 0; s < 4; ++s) {
    float a0 = av[0].x * tm[s][0];
    float a1 = av[0].y * tm[s][1];
    a0 = fmaf(av[0].z, tm[s][2],  a0);
    a1 = fmaf(av[0].w, tm[s][3],  a1);
    a0 = fmaf(av[1].x, tm[s][4],  a0);
    a1 = fmaf(av[1].y, tm[s][5],  a1);
    a0 = fmaf(av[1].z, tm[s][6],  a0);
    a1 = fmaf(av[1].w, tm[s][7],  a1);
    a0 = fmaf(av[2].x, tm[s][8],  a0);
    a1 = fmaf(av[2].y, tm[s][9],  a1);
    a0 = fmaf(av[2].z, tm[s][10], a0);
    a1 = fmaf(av[2].w, tm[s][11], a1);
    a0 = fmaf(av[3].x, tm[s][12], a0);
    a1 = fmaf(av[3].y, tm[s][13], a1);
    a0 = fmaf(av[3].z, tm[s][14], a0);
    a1 = fmaf(av[3].w, tm[s][15], a1);
    z[s] = a0 + a1;
  }
  #pragma unroll
  for (int s = 0; s < 4; ++s) {
    z[s] += __shfl_xor(z[s], 1, 64);
    z[s] += __shfl_xor(z[s], 2, 64);
    z[s] += __shfl_xor(z[s], 4, 64);
  }
}

__global__ __launch_bounds__(256, 1)
void soft_viterbi_kernel(const float* __restrict__ trans,
                         const float* __restrict__ emis,
                         const float* __restrict__ prior,
                         float* __restrict__ out) {
  const int b    = blockIdx.x;
  const int tid  = threadIdx.x;
  const int w    = tid >> 6;
  const int lane = tid & 63;
  const int q    = lane >> 3;      // quad id: 4 contiguous states
  const int kc   = lane & 7;       // k-chunk: granules kc+8i
  const int n0   = 32 * w + 4 * q; // first owned state

  __shared__ __align__(16) float ubuf[2][NN];  // ping-pong alpha~ / q exchange
  __shared__ __align__(16) float sarr[TT];     // sarr[t] = 1/alpha~_t[0]
  __shared__ __align__(16) float red[NN];      // rowsum, then reduction scratch

  const float* embq = emis + (size_t)b * TT * NN + n0;  // float4 emission loads
  float* outb = out + (size_t)b * TT * NN;

  // ---- issue early global loads (prior, em[0..3]) ----
  float4 pr4 = *(const float4*)(prior + n0);
  float4 em0 = *(const float4*)(embq);
  float4 e1  = *(const float4*)(embq + 1 * NN);
  float4 e2  = *(const float4*)(embq + 2 * NN);
  float4 e3  = *(const float4*)(embq + 3 * NN);
  pr4.x = fmaxf(pr4.x, EPSC); pr4.y = fmaxf(pr4.y, EPSC);
  pr4.z = fmaxf(pr4.z, EPSC); pr4.w = fmaxf(pr4.w, EPSC);

  // ---- row sums of clipped transition ----
  if (tid < NN) {
    const float4* row = (const float4*)(trans + tid * NN);
    float s = 0.f;
    #pragma unroll 8
    for (int j = 0; j < NN / 4; ++j) {
      float4 v = row[j];
      s += fmaxf(v.x, EPSC) + fmaxf(v.y, EPSC) + fmaxf(v.z, EPSC) + fmaxf(v.w, EPSC);
    }
    red[tid] = s;
  }
  __syncthreads();

  // ---- forward fragment: tf[s][4i+c] = Tn[p][n0+s], p=(kc+8i)*4+c ----
  float tf[4][16];
  #pragma unroll
  for (int i = 0; i < 4; ++i) {
    #pragma unroll
    for (int c = 0; c < 4; ++c) {
      const int p = (kc + 8 * i) * 4 + c;
      const float4 tv = *(const float4*)(trans + p * NN + n0);
      const float rp = red[p];
      tf[0][4*i+c] = fmaxf(tv.x, EPSC) / rp;
      tf[1][4*i+c] = fmaxf(tv.y, EPSC) / rp;
      tf[2][4*i+c] = fmaxf(tv.z, EPSC) / rp;
      tf[3][4*i+c] = fmaxf(tv.w, EPSC) / rp;
    }
  }
  // ---- backward fragment: tb[s][4i+c] = Tn[n0+s][(kc+8i)*4+c] ----
  float tb[4][16];
  #pragma unroll
  for (int s = 0; s < 4; ++s) {
    const float inv = 1.0f / red[n0 + s];
    const float4* rr = (const float4*)(trans + (n0 + s) * NN);
    #pragma unroll
    for (int i = 0; i < 4; ++i) {
      const float4 tv = rr[kc + 8 * i];
      tb[s][4*i+0] = fmaxf(tv.x, EPSC) * inv;
      tb[s][4*i+1] = fmaxf(tv.y, EPSC) * inv;
      tb[s][4*i+2] = fmaxf(tv.z, EPSC) * inv;
      tb[s][4*i+3] = fmaxf(tv.w, EPSC) * inv;
    }
  }

  // ---- prior normalization (kc==0 lanes contribute 4 states each) ----
  float vv = (kc == 0) ? ((pr4.x + pr4.y) + (pr4.z + pr4.w)) : 0.f;
  #pragma unroll
  for (int m = 1; m < 64; m <<= 1) vv += __shfl_xor(vv, m, 64);
  __syncthreads();                 // all tf/tb reads of red[] complete
  if (lane == 0) red[w] = vv;
  __syncthreads();
  const float psum = (red[0] + red[1]) + (red[2] + red[3]);

  // ---- u0 = alpha~_0 ----
  float an0 = (pr4.x / psum) * __expf(em0.x);
  float an1 = (pr4.y / psum) * __expf(em0.y);
  float an2 = (pr4.z / psum) * __expf(em0.z);
  float an3 = (pr4.w / psum) * __expf(em0.w);
  if (kc == 0) {
    float4 a4 = make_float4(an0, an1, an2, an3);
    *(float4*)&ubuf[0][n0] = a4;
    *(float4*)(outb + n0) = a4;
  }
  float dc0 = __expf(e1.x), dc1 = __expf(e1.y), dc2 = __expf(e1.z), dc3 = __expf(e1.w); // d_1
  float4 eh1 = e2;                 // em[2]
  float4 eh2 = e3;                 // em[3]
  float dl0 = dc0, dl1 = dc1, dl2 = dc2, dl3 = dc3;  // d_last
  bar_lds();                       // publish ubuf[0]

  // ================= forward =================
  for (int t = 1; t < TT; ++t) {
    const float* rb = ubuf[(t - 1) & 1];
    const float r0 = rb[0];                       // broadcast read, lands early
    const float4* rb4 = (const float4*)rb;
    float4 av[4];
    av[0] = rb4[kc];  av[1] = rb4[kc + 8];
    av[2] = rb4[kc + 16]; av[3] = rb4[kc + 24];
    float z[4];
    dot16(av, tf, z);
    const float rinv = 1.0f / r0;                 // off-chain (r0 early)
    if (t == TT - 1) { dl0 = dc0; dl1 = dc1; dl2 = dc2; dl3 = dc3; }
    an0 = (dc0 * rinv) * z[0];
    an1 = (dc1 * rinv) * z[1];
    an2 = (dc2 * rinv) * z[2];
    an3 = (dc3 * rinv) * z[3];
    dc0 = __expf(eh1.x); dc1 = __expf(eh1.y);     // d_{t+1}, off-chain
    dc2 = __expf(eh1.z); dc3 = __expf(eh1.w);
    eh1 = eh2;
    const int tpre = (t + 3 < TT) ? (t + 3) : (TT - 1);
    eh2 = *(const float4*)(embq + (size_t)tpre * NN);  // prefetch em[t+3]
    if (kc == 0) {
      float4 a4 = make_float4(an0, an1, an2, an3);
      *(float4*)&ubuf[t & 1][n0] = a4;
      if (t < TT - 1) *(float4*)(outb + (size_t)t * NN + n0) = a4;  // stash
    }
    if (tid == 0) sarr[t - 1] = rinv;             // r_{t-1}
    bar_lds();
  }

  // ================= final softmax =================
  float v2 = (kc == 0) ? ((an0 + an1) + (an2 + an3)) : 0.f;
  #pragma unroll
  for (int m = 1; m < 64; m <<= 1) v2 += __shfl_xor(v2, m, 64);
  if (lane == 0) red[w] = v2;
  __syncthreads();
  const float total = (red[0] + red[1]) + (red[2] + red[3]);
  const float itot = 1.0f / total;
  float pc0 = an0 * itot, pc1 = an1 * itot, pc2 = an2 * itot, pc3 = an3 * itot;
  if (kc == 0) *(float4*)(outb + (size_t)(TT - 1) * NN + n0) = make_float4(pc0, pc1, pc2, pc3);

  // One-time drain: forward alpha-stash stores must be visible before the
  // backward pass re-reads them (same-wave vmem ops are not address-ordered).
  asm volatile("s_waitcnt vmcnt(0)" ::: "memory");

  // ---- backward pipeline init (issue loads early) ----
  float4 ec_cur = *(const float4*)(outb + (size_t)(TT - 2) * NN + n0);  // alpha~_{T-2}
  float4 ec_h   = *(const float4*)(outb + (size_t)(TT - 3) * NN + n0);  // alpha~_{T-3}
  float4 em_b1  = *(const float4*)(embq + (size_t)(TT - 2) * NN);       // em[T-2]
  float4 em_b2  = *(const float4*)(embq + (size_t)(TT - 3) * NN);       // em[T-3]
  const float sl = sarr[TT - 2];
  float g0 = dl0 * sl / fmaxf(an0, TINY);
  float g1 = dl1 * sl / fmaxf(an1, TINY);
  float g2 = dl2 * sl / fmaxf(an2, TINY);
  float g3 = dl3 * sl / fmaxf(an3, TINY);

  // ================= backward =================
  for (int t = TT - 2; t >= 0; --t) {
    if (kc == 0) {
      float4 qv = make_float4(pc0 * g0, pc1 * g1, pc2 * g2, pc3 * g3);
      *(float4*)&ubuf[t & 1][n0] = qv;
    }
    // off-chain prep for iter t-1:
    const float sr = sarr[(t > 0) ? (t - 1) : 0];
    const float gn0 = __expf(em_b1.x) * sr / fmaxf(ec_cur.x, TINY);
    const float gn1 = __expf(em_b1.y) * sr / fmaxf(ec_cur.y, TINY);
    const float gn2 = __expf(em_b1.z) * sr / fmaxf(ec_cur.z, TINY);
    const float gn3 = __expf(em_b1.w) * sr / fmaxf(ec_cur.w, TINY);
    em_b1 = em_b2;
    const int tp = (t >= 2) ? (t - 2) : 0;
    em_b2 = *(const float4*)(embq + (size_t)tp * NN);
    bar_lds();
    const float4* qb4 = (const float4*)ubuf[t & 1];
    float4 av[4];
    av[0] = qb4[kc];  av[1] = qb4[kc + 8];
    av[2] = qb4[kc + 16]; av[3] = qb4[kc + 24];
    float z[4];
    dot16(av, tb, z);
    pc0 = ec_cur.x * z[0];
    pc1 = ec_cur.y * z[1];
    pc2 = ec_cur.z * z[2];
    pc3 = ec_cur.w * z[3];
    if (kc == 0) *(float4*)(outb + (size_t)t * NN + n0) = make_float4(pc0, pc1, pc2, pc3);
    g0 = gn0; g1 = gn1; g2 = gn2; g3 = gn3;
    ec_cur = ec_h;                                // alpha~_{t-1}
    ec_h = *(const float4*)(outb + (size_t)tp * NN + n0);  // prefetch alpha~_{t-2}
  }
}

extern "C" void kernel_launch(void* const* d_in, const int* in_sizes, int n_in,
                              void* d_out, int out_size, void* d_ws, size_t ws_size,
                              hipStream_t stream) {
  (void)in_sizes; (void)n_in; (void)d_ws; (void)ws_size; (void)out_size;
  const float* trans = (const float*)d_in[0];
  const float* emis  = (const float*)d_in[1];
  const float* prior = (const float*)d_in[2];
  float* out = (float*)d_out;
  soft_viterbi_kernel<<<dim3(BB), dim3(256), 0, stream>>>(trans, emis, prior, out);
}

// Round 3
// 452.292 us; speedup vs baseline: 1.3101x; 1.3101x over previous
//
#include <hip/hip_runtime.h>
#include <math.h>

// Soft-Viterbi structured decoding: B=32, T=512, N=128, fp32.
// Linear-space formulation, ONE barrier + ONE LDS round trip per step.
//
// Round-3: attack the serial dependency chain (LDS BW/conflicts proved
// irrelevant in round 2 — conflicts 8.4M -> 0 with no time change).
//  * Tile G=2 states x C=32 K-chunk per lane: combine group = 4 consecutive
//    lanes, reduced with DPP quad_perm adds (pure VALU) instead of
//    __shfl_xor (which lowers to ds_swizzle = DS-latency on the chain).
//  * Barrier = single fused asm "s_waitcnt lgkmcnt(0); s_barrier" with
//    "memory" clobber only — scheduler free to hide prefetch ops.
//  * 2 exps/step (float2 state block), branchless d_last.
// Read pattern per step: lane k=lane&3 reads granules k+4i (i=0..7):
// per instruction 4 granules x 4 banks = 16 distinct banks, 16-way
// broadcast — zero conflicts.
//
// Forward:  alpha~_t = d_t * r_{t-1} * Z_raw,t ;  Z_raw,t[n] = sum_p T[p,n] alpha~_{t-1}[p]
// Backward: p_t[m] = alpha~_t[m] * sum_n q[n] T[m,n],
//           q[n] = p_{t+1}[n] * d_{t+1}[n] * r_t / alpha~_{t+1}[n]  (prefetched off-chain).

#define TT 512
#define BB 32
#define NN 128
#define EPSC 1e-10f
#define TINY 1e-33f

// Fused LDS-drain + barrier. No vmcnt wait (global ops stay in flight);
// "memory" clobber orders all LDS accesses across it.
#define BAR() asm volatile("s_waitcnt lgkmcnt(0)\n\ts_barrier" ::: "memory")

// DPP quad_perm lane swaps (xor 1 / xor 2 within each 4-lane quad).
__device__ __forceinline__ float qswap1(float x) {
  return __int_as_float(__builtin_amdgcn_mov_dpp(__float_as_int(x), 0xB1, 0xF, 0xF, true));
}
__device__ __forceinline__ float qswap2(float x) {
  return __int_as_float(__builtin_amdgcn_mov_dpp(__float_as_int(x), 0x4E, 0xF, 0xF, true));
}

// 2-state x 32-element partial dot + 4-lane DPP combine. All 4 lanes of
// the quad end with the full 128-length sums in z[0..1].
__device__ __forceinline__ void dot32(const float4 av[8], const float tm[2][32], float z[2]) {
  #pragma unroll
  for (int s = 0; s < 2; ++s) {
    float a0 = 0.f, a1 = 0.f, a2 = 0.f, a3 = 0.f;
    #pragma unroll
    for (int i = 0; i < 8; ++i) {
      a0 = fmaf(av[i].x, tm[s][4*i+0], a0);
      a1 = fmaf(av[i].y, tm[s][4*i+1], a1);
      a2 = fmaf(av[i].z, tm[s][4*i+2], a2);
      a3 = fmaf(av[i].w, tm[s][4*i+3], a3);
    }
    float zz = (a0 + a1) + (a2 + a3);
    zz += qswap1(zz);
    zz += qswap2(zz);
    z[s] = zz;
  }
}

__global__ __launch_bounds__(256, 1)
void soft_viterbi_kernel(const float* __restrict__ trans,
                         const float* __restrict__ emis,
                         const float* __restrict__ prior,
                         float* __restrict__ out) {
  const int b    = blockIdx.x;
  const int tid  = threadIdx.x;
  const int w    = tid >> 6;
  const int lane = tid & 63;
  const int k    = lane & 3;             // k-chunk within quad
  const int pid  = lane >> 2;            // state-pair id within wave (0..15)
  const int n0   = 32 * w + 2 * pid;     // first owned state (2 per lane)

  __shared__ __align__(16) float ubuf[2][NN];  // ping-pong alpha~ / q exchange
  __shared__ __align__(16) float sarr[TT];     // sarr[t] = 1/alpha~_t[0]
  __shared__ __align__(16) float red[NN];      // rowsum, then reduction scratch

  const float* embq = emis + (size_t)b * TT * NN + n0;  // float2 emission loads
  float* outb = out + (size_t)b * TT * NN;

  // ---- issue early global loads (prior, em[0..3]) ----
  float2 pr2 = *(const float2*)(prior + n0);
  float2 em0 = *(const float2*)(embq);
  float2 e1  = *(const float2*)(embq + 1 * NN);
  float2 e2  = *(const float2*)(embq + 2 * NN);
  float2 e3  = *(const float2*)(embq + 3 * NN);
  pr2.x = fmaxf(pr2.x, EPSC); pr2.y = fmaxf(pr2.y, EPSC);

  // ---- row sums of clipped transition ----
  if (tid < NN) {
    const float4* row = (const float4*)(trans + tid * NN);
    float s = 0.f;
    #pragma unroll 8
    for (int j = 0; j < NN / 4; ++j) {
      float4 v = row[j];
      s += fmaxf(v.x, EPSC) + fmaxf(v.y, EPSC) + fmaxf(v.z, EPSC) + fmaxf(v.w, EPSC);
    }
    red[tid] = s;
  }
  __syncthreads();

  // ---- forward fragment: tf[s][4i+c] = Tn[p][n0+s], p = 4*(k+4i)+c ----
  float tf[2][32];
  #pragma unroll
  for (int i = 0; i < 8; ++i) {
    #pragma unroll
    for (int c = 0; c < 4; ++c) {
      const int p = 4 * (k + 4 * i) + c;
      const float2 tv = *(const float2*)(trans + p * NN + n0);
      const float rp = red[p];
      tf[0][4*i+c] = fmaxf(tv.x, EPSC) / rp;
      tf[1][4*i+c] = fmaxf(tv.y, EPSC) / rp;
    }
  }
  // ---- backward fragment: tb[s][4i+c] = Tn[n0+s][4*(k+4i)+c] ----
  float tb[2][32];
  #pragma unroll
  for (int s = 0; s < 2; ++s) {
    const float inv = 1.0f / red[n0 + s];
    const float4* rr = (const float4*)(trans + (n0 + s) * NN);
    #pragma unroll
    for (int i = 0; i < 8; ++i) {
      const float4 tv = rr[k + 4 * i];
      tb[s][4*i+0] = fmaxf(tv.x, EPSC) * inv;
      tb[s][4*i+1] = fmaxf(tv.y, EPSC) * inv;
      tb[s][4*i+2] = fmaxf(tv.z, EPSC) * inv;
      tb[s][4*i+3] = fmaxf(tv.w, EPSC) * inv;
    }
  }

  // ---- prior normalization (k==0 lanes contribute their 2 states) ----
  float vv = (k == 0) ? (pr2.x + pr2.y) : 0.f;
  #pragma unroll
  for (int m = 1; m < 64; m <<= 1) vv += __shfl_xor(vv, m, 64);
  __syncthreads();                 // all tf/tb reads of red[] complete
  if (lane == 0) red[w] = vv;
  __syncthreads();
  const float psum = (red[0] + red[1]) + (red[2] + red[3]);

  // ---- u0 = alpha~_0 ----
  float an0 = (pr2.x / psum) * __expf(em0.x);
  float an1 = (pr2.y / psum) * __expf(em0.y);
  if (k == 0) {
    float2 a2 = make_float2(an0, an1);
    *(float2*)&ubuf[0][n0] = a2;
    *(float2*)(outb + n0) = a2;
  }
  float dc0 = __expf(e1.x), dc1 = __expf(e1.y);  // d_1
  float2 eh1 = e2;                 // em[2]
  float2 eh2 = e3;                 // em[3]
  float dl0 = dc0, dl1 = dc1;      // d_last
  BAR();                           // publish ubuf[0]

  // ================= forward =================
  for (int t = 1; t < TT; ++t) {
    const float* rb = ubuf[(t - 1) & 1];
    const float r0 = rb[0];                       // broadcast read, lands early
    const float4* rb4 = (const float4*)rb;
    float4 av[8];
    #pragma unroll
    for (int i = 0; i < 8; ++i) av[i] = rb4[k + 4 * i];
    float z[2];
    dot32(av, tf, z);
    const float rinv = 1.0f / r0;                 // off-chain (r0 early)
    dl0 = dc0; dl1 = dc1;                         // branchless d_last save
    an0 = (dc0 * rinv) * z[0];
    an1 = (dc1 * rinv) * z[1];
    dc0 = __expf(eh1.x); dc1 = __expf(eh1.y);     // d_{t+1}, off-chain
    eh1 = eh2;
    const int tpre = (t + 3 < TT) ? (t + 3) : (TT - 1);
    eh2 = *(const float2*)(embq + (size_t)tpre * NN);  // prefetch em[t+3]
    if (k == 0) {
      float2 a2 = make_float2(an0, an1);
      *(float2*)&ubuf[t & 1][n0] = a2;
      if (t < TT - 1) *(float2*)(outb + (size_t)t * NN + n0) = a2;  // stash
    }
    if (tid == 0) sarr[t - 1] = rinv;             // r_{t-1}
    BAR();
  }

  // ================= final softmax =================
  float v2 = (k == 0) ? (an0 + an1) : 0.f;
  #pragma unroll
  for (int m = 1; m < 64; m <<= 1) v2 += __shfl_xor(v2, m, 64);
  if (lane == 0) red[w] = v2;
  __syncthreads();
  const float total = (red[0] + red[1]) + (red[2] + red[3]);
  const float itot = 1.0f / total;
  float pc0 = an0 * itot, pc1 = an1 * itot;
  if (k == 0) *(float2*)(outb + (size_t)(TT - 1) * NN + n0) = make_float2(pc0, pc1);

  // One-time drain: forward alpha-stash stores must be visible before the
  // backward pass re-reads them (same-wave vmem ops are not address-ordered).
  asm volatile("s_waitcnt vmcnt(0)" ::: "memory");

  // ---- backward pipeline init (issue loads early) ----
  float2 ec_cur = *(const float2*)(outb + (size_t)(TT - 2) * NN + n0);  // alpha~_{T-2}
  float2 ec_h   = *(const float2*)(outb + (size_t)(TT - 3) * NN + n0);  // alpha~_{T-3}
  float2 em_b1  = *(const float2*)(embq + (size_t)(TT - 2) * NN);       // em[T-2]
  float2 em_b2  = *(const float2*)(embq + (size_t)(TT - 3) * NN);       // em[T-3]
  const float sl = sarr[TT - 2];
  float g0 = dl0 * sl / fmaxf(an0, TINY);
  float g1 = dl1 * sl / fmaxf(an1, TINY);

  // ================= backward =================
  for (int t = TT - 2; t >= 0; --t) {
    if (k == 0) {
      *(float2*)&ubuf[t & 1][n0] = make_float2(pc0 * g0, pc1 * g1);
    }
    // off-chain prep for iter t-1:
    const float sr = sarr[(t > 0) ? (t - 1) : 0];
    const float gn0 = __expf(em_b1.x) * sr / fmaxf(ec_cur.x, TINY);
    const float gn1 = __expf(em_b1.y) * sr / fmaxf(ec_cur.y, TINY);
    em_b1 = em_b2;
    const int tp = (t >= 2) ? (t - 2) : 0;
    em_b2 = *(const float2*)(embq + (size_t)tp * NN);
    BAR();
    const float4* qb4 = (const float4*)ubuf[t & 1];
    float4 av[8];
    #pragma unroll
    for (int i = 0; i < 8; ++i) av[i] = qb4[k + 4 * i];
    float z[2];
    dot32(av, tb, z);
    pc0 = ec_cur.x * z[0];
    pc1 = ec_cur.y * z[1];
    if (k == 0) *(float2*)(outb + (size_t)t * NN + n0) = make_float2(pc0, pc1);
    g0 = gn0; g1 = gn1;
    ec_cur = ec_h;                                // alpha~_{t-1}
    ec_h = *(const float2*)(outb + (size_t)tp * NN + n0);  // prefetch alpha~_{t-2}
  }
}

extern "C" void kernel_launch(void* const* d_in, const int* in_sizes, int n_in,
                              void* d_out, int out_size, void* d_ws, size_t ws_size,
                              hipStream_t stream) {
  (void)in_sizes; (void)n_in; (void)d_ws; (void)ws_size; (void)out_size;
  const float* trans = (const float*)d_in[0];
  const float* emis  = (const float*)d_in[1];
  const float* prior = (const float*)d_in[2];
  float* out = (float*)d_out;
  soft_viterbi_kernel<<<dim3(BB), dim3(256), 0, stream>>>(trans, emis, prior, out);
}

// Round 4
// 424.803 us; speedup vs baseline: 1.3949x; 1.0647x over previous
//
#include <hip/hip_runtime.h>
#include <math.h>

// Soft-Viterbi structured decoding: B=32, T=512, N=128, fp32.
// Linear-space formulation, ONE barrier + ONE LDS round trip per step.
//
// Round-4: cut VALU issue on the serial chain (1 wave/SIMD => every instr
// costs 2 cy of step latency).
//  * v_pk_fma_f32 packed math: 64 scalar FMA -> 32 pk ops per step
//    (v2f ext-vector + __builtin_elementwise_fma).
//  * t-loop unrolled x2: static ping-pong buffers, no per-step d_last
//    copies (emission clamp makes dc == d_{T-1} at loop exit for free).
//  * Combine stays DPP quad_perm (pure VALU, round-3 verified).
// Layout as round 3: lane k=lane&3 reads granules k+4i (16-way broadcast,
// zero bank conflicts), 2 states per lane, 4-lane quad combine.

#define TT 512
#define BB 32
#define NN 128
#define EPSC 1e-10f
#define TINY 1e-33f

typedef float v2f __attribute__((ext_vector_type(2)));

// Fused LDS-drain + barrier. No vmcnt wait (global ops stay in flight).
#define BAR() asm volatile("s_waitcnt lgkmcnt(0)\n\ts_barrier" ::: "memory")

// DPP quad_perm lane swaps (xor 1 / xor 2 within each 4-lane quad).
__device__ __forceinline__ float qswap1(float x) {
  return __int_as_float(__builtin_amdgcn_mov_dpp(__float_as_int(x), 0xB1, 0xF, 0xF, true));
}
__device__ __forceinline__ float qswap2(float x) {
  return __int_as_float(__builtin_amdgcn_mov_dpp(__float_as_int(x), 0x4E, 0xF, 0xF, true));
}

// 32-element partial dot via 16 packed FMAs (4 independent chains).
__device__ __forceinline__ float dotpk16(const v2f av[16], const v2f tm[16]) {
  v2f a0 = av[0] * tm[0];
  v2f a1 = av[1] * tm[1];
  v2f a2 = av[2] * tm[2];
  v2f a3 = av[3] * tm[3];
  #pragma unroll
  for (int j = 4; j < 16; j += 4) {
    a0 = __builtin_elementwise_fma(av[j+0], tm[j+0], a0);
    a1 = __builtin_elementwise_fma(av[j+1], tm[j+1], a1);
    a2 = __builtin_elementwise_fma(av[j+2], tm[j+2], a2);
    a3 = __builtin_elementwise_fma(av[j+3], tm[j+3], a3);
  }
  v2f s = (a0 + a1) + (a2 + a3);
  return s.x + s.y;
}

__global__ __launch_bounds__(256, 1)
void soft_viterbi_kernel(const float* __restrict__ trans,
                         const float* __restrict__ emis,
                         const float* __restrict__ prior,
                         float* __restrict__ out) {
  const int b    = blockIdx.x;
  const int tid  = threadIdx.x;
  const int w    = tid >> 6;
  const int lane = tid & 63;
  const int k    = lane & 3;             // k-chunk within quad
  const int pid  = lane >> 2;            // state-pair id within wave (0..15)
  const int n0   = 32 * w + 2 * pid;     // first owned state (2 per lane)

  __shared__ __align__(16) float ubuf[2][NN];  // ping-pong alpha~ / q exchange
  __shared__ __align__(16) float sarr[TT];     // sarr[t] = 1/alpha~_t[0]
  __shared__ __align__(16) float red[NN];      // rowsum, then reduction scratch

  const float* embq = emis + (size_t)b * TT * NN + n0;  // float2 emission loads
  float* outb = out + (size_t)b * TT * NN;

  // ---- issue early global loads (prior, em[0..3]) ----
  float2 pr2 = *(const float2*)(prior + n0);
  float2 em0 = *(const float2*)(embq);
  float2 e1  = *(const float2*)(embq + 1 * NN);
  float2 e2  = *(const float2*)(embq + 2 * NN);
  float2 e3  = *(const float2*)(embq + 3 * NN);
  pr2.x = fmaxf(pr2.x, EPSC); pr2.y = fmaxf(pr2.y, EPSC);

  // ---- row sums of clipped transition ----
  if (tid < NN) {
    const float4* row = (const float4*)(trans + tid * NN);
    float s = 0.f;
    #pragma unroll 8
    for (int j = 0; j < NN / 4; ++j) {
      float4 v = row[j];
      s += fmaxf(v.x, EPSC) + fmaxf(v.y, EPSC) + fmaxf(v.z, EPSC) + fmaxf(v.w, EPSC);
    }
    red[tid] = s;
  }
  __syncthreads();

  // ---- forward fragment (pk-packed): tf2[s][2i+(c>>1)][c&1] = Tn[p][n0+s], p=4(k+4i)+c ----
  v2f tf2[2][16];
  #pragma unroll
  for (int i = 0; i < 8; ++i) {
    #pragma unroll
    for (int c = 0; c < 4; ++c) {
      const int p = 4 * (k + 4 * i) + c;
      const float2 tv = *(const float2*)(trans + p * NN + n0);
      const float rp = red[p];
      tf2[0][2*i + (c >> 1)][c & 1] = fmaxf(tv.x, EPSC) / rp;
      tf2[1][2*i + (c >> 1)][c & 1] = fmaxf(tv.y, EPSC) / rp;
    }
  }
  // ---- backward fragment: tb2[s][2i..][..] = Tn[n0+s][4(k+4i)+c] ----
  v2f tb2[2][16];
  #pragma unroll
  for (int s = 0; s < 2; ++s) {
    const float inv = 1.0f / red[n0 + s];
    const float4* rr = (const float4*)(trans + (n0 + s) * NN);
    #pragma unroll
    for (int i = 0; i < 8; ++i) {
      const float4 tv = rr[k + 4 * i];
      tb2[s][2*i+0][0] = fmaxf(tv.x, EPSC) * inv;
      tb2[s][2*i+0][1] = fmaxf(tv.y, EPSC) * inv;
      tb2[s][2*i+1][0] = fmaxf(tv.z, EPSC) * inv;
      tb2[s][2*i+1][1] = fmaxf(tv.w, EPSC) * inv;
    }
  }

  // ---- prior normalization ----
  float vv = (k == 0) ? (pr2.x + pr2.y) : 0.f;
  #pragma unroll
  for (int m = 1; m < 64; m <<= 1) vv += __shfl_xor(vv, m, 64);
  __syncthreads();                 // all tf/tb reads of red[] complete
  if (lane == 0) red[w] = vv;
  __syncthreads();
  const float psum = (red[0] + red[1]) + (red[2] + red[3]);

  // ---- u0 = alpha~_0 ----
  float an0 = (pr2.x / psum) * __expf(em0.x);
  float an1 = (pr2.y / psum) * __expf(em0.y);
  if (k == 0) {
    float2 a2v = make_float2(an0, an1);
    *(float2*)&ubuf[0][n0] = a2v;
    *(float2*)(outb + n0) = a2v;
  }
  float dc0 = __expf(e1.x), dc1 = __expf(e1.y);  // d_1
  float2 eh1 = e2;                 // em[t+1] invariant
  float2 eh2 = e3;                 // em[t+2] invariant
  BAR();                           // publish ubuf[0]

  // ================= forward =================
  // Invariant entering step t: dc = d_t, eh1 = em[t+1], eh2 = em[t+2]
  // (clamped at the end, which leaves dc = d_{T-1} after the last step).
  auto fstep = [&](const float* rb, float* wb, int t) {
    const float r0 = rb[0];                       // broadcast read, lands early
    const float4* rb4 = (const float4*)rb;
    float4 a4[8];
    #pragma unroll
    for (int i = 0; i < 8; ++i) a4[i] = rb4[k + 4 * i];
    v2f av[16];
    #pragma unroll
    for (int i = 0; i < 8; ++i) {
      av[2*i+0][0] = a4[i].x; av[2*i+0][1] = a4[i].y;
      av[2*i+1][0] = a4[i].z; av[2*i+1][1] = a4[i].w;
    }
    float z0 = dotpk16(av, tf2[0]);
    float z1 = dotpk16(av, tf2[1]);
    z0 += qswap1(z0); z0 += qswap2(z0);
    z1 += qswap1(z1); z1 += qswap2(z1);
    const float rinv = 1.0f / r0;                 // off-chain (r0 early)
    an0 = (dc0 * rinv) * z0;
    an1 = (dc1 * rinv) * z1;
    dc0 = __expf(eh1.x); dc1 = __expf(eh1.y);     // d_{t+1}, off-chain
    eh1 = eh2;
    const int tpre = (t + 3 < TT) ? (t + 3) : (TT - 1);
    eh2 = *(const float2*)(embq + (size_t)tpre * NN);  // prefetch em[t+3]
    if (k == 0) {
      float2 a2v = make_float2(an0, an1);
      *(float2*)(wb + n0) = a2v;
      if (t < TT - 1) *(float2*)(outb + (size_t)t * NN + n0) = a2v;  // stash
    }
    if (tid == 0) sarr[t - 1] = rinv;             // r_{t-1}
    BAR();
  };

  fstep(ubuf[0], ubuf[1], 1);                     // peel t=1
  for (int t = 2; t < TT - 1; t += 2) {
    fstep(ubuf[1], ubuf[0], t);
    fstep(ubuf[0], ubuf[1], t + 1);
  }
  const float dl0 = dc0, dl1 = dc1;               // = d_{T-1} (clamped pipeline)

  // ================= final softmax =================
  float v2 = (k == 0) ? (an0 + an1) : 0.f;
  #pragma unroll
  for (int m = 1; m < 64; m <<= 1) v2 += __shfl_xor(v2, m, 64);
  if (lane == 0) red[w] = v2;
  __syncthreads();
  const float total = (red[0] + red[1]) + (red[2] + red[3]);
  const float itot = 1.0f / total;
  float pc0 = an0 * itot, pc1 = an1 * itot;
  if (k == 0) *(float2*)(outb + (size_t)(TT - 1) * NN + n0) = make_float2(pc0, pc1);

  // One-time drain: forward alpha-stash stores must be visible before the
  // backward pass re-reads them (same-wave vmem ops are not address-ordered).
  asm volatile("s_waitcnt vmcnt(0)" ::: "memory");

  // ---- backward pipeline init (issue loads early) ----
  float2 ec_cur = *(const float2*)(outb + (size_t)(TT - 2) * NN + n0);  // alpha~_{T-2}
  float2 ec_h   = *(const float2*)(outb + (size_t)(TT - 3) * NN + n0);  // alpha~_{T-3}
  float2 em_b1  = *(const float2*)(embq + (size_t)(TT - 2) * NN);       // em[T-2]
  float2 em_b2  = *(const float2*)(embq + (size_t)(TT - 3) * NN);       // em[T-3]
  const float sl = sarr[TT - 2];
  float g0 = dl0 * sl / fmaxf(an0, TINY);
  float g1 = dl1 * sl / fmaxf(an1, TINY);

  // ================= backward =================
  // Invariant entering step t: pc = p_{t+1}, g = g_t, ec_cur = alpha~_t,
  // ec_h = alpha~_{t-1}, em_b1 = em[t], em_b2 = em[t-1].
  auto bstep = [&](float* xb, int t) {
    if (k == 0) *(float2*)(xb + n0) = make_float2(pc0 * g0, pc1 * g1);
    const float sr = sarr[(t > 0) ? (t - 1) : 0];
    const float gn0 = __expf(em_b1.x) * sr / fmaxf(ec_cur.x, TINY);
    const float gn1 = __expf(em_b1.y) * sr / fmaxf(ec_cur.y, TINY);
    em_b1 = em_b2;
    const int tp = (t >= 2) ? (t - 2) : 0;
    em_b2 = *(const float2*)(embq + (size_t)tp * NN);
    BAR();
    const float4* qb4 = (const float4*)xb;
    float4 a4[8];
    #pragma unroll
    for (int i = 0; i < 8; ++i) a4[i] = qb4[k + 4 * i];
    v2f av[16];
    #pragma unroll
    for (int i = 0; i < 8; ++i) {
      av[2*i+0][0] = a4[i].x; av[2*i+0][1] = a4[i].y;
      av[2*i+1][0] = a4[i].z; av[2*i+1][1] = a4[i].w;
    }
    float z0 = dotpk16(av, tb2[0]);
    float z1 = dotpk16(av, tb2[1]);
    z0 += qswap1(z0); z0 += qswap2(z0);
    z1 += qswap1(z1); z1 += qswap2(z1);
    pc0 = ec_cur.x * z0;
    pc1 = ec_cur.y * z1;
    if (k == 0) *(float2*)(outb + (size_t)t * NN + n0) = make_float2(pc0, pc1);
    g0 = gn0; g1 = gn1;
    ec_cur = ec_h;                                // alpha~_{t-1}
    ec_h = *(const float2*)(outb + (size_t)tp * NN + n0);  // prefetch alpha~_{t-2}
  };

  bstep(ubuf[(TT - 2) & 1], TT - 2);              // peel t=510
  for (int t = TT - 3; t > 0; t -= 2) {
    bstep(ubuf[t & 1], t);
    bstep(ubuf[(t - 1) & 1], t - 1);
  }
}

extern "C" void kernel_launch(void* const* d_in, const int* in_sizes, int n_in,
                              void* d_out, int out_size, void* d_ws, size_t ws_size,
                              hipStream_t stream) {
  (void)in_sizes; (void)n_in; (void)d_ws; (void)ws_size; (void)out_size;
  const float* trans = (const float*)d_in[0];
  const float* emis  = (const float*)d_in[1];
  const float* prior = (const float*)d_in[2];
  float* out = (float*)d_out;
  soft_viterbi_kernel<<<dim3(BB), dim3(256), 0, stream>>>(trans, emis, prior, out);
}

// Round 5
// 420.237 us; speedup vs baseline: 1.4100x; 1.0109x over previous
//
#include <hip/hip_runtime.h>
#include <math.h>

// Soft-Viterbi structured decoding: B=32, T=512, N=128, fp32.
// Linear-space formulation, ONE barrier + ONE LDS round trip per step.
//
// Round-5: depth-4 register ring buffers for all streamed global operands.
// Round-4's prefetch had only 1 step of slack (eh1=eh2 register copy forced
// a vmcnt wait on a load issued one step earlier; same for ec_h/em_b2 in
// backward) — L3/HBM latency (~400-900cy) exceeds one step (~700cy) minus
// issue time, leaking VMEM stalls into every step. Rings give 4 steps
// (~1.4us) of slack; loops unrolled x4 so ring slots are static registers.
// Everything else (layout, pk-FMA dot, DPP quad combine, LDS-only barrier)
// unchanged from round 4.

#define TT 512
#define BB 32
#define NN 128
#define EPSC 1e-10f
#define TINY 1e-33f

typedef float v2f __attribute__((ext_vector_type(2)));

// Fused LDS-drain + barrier. No vmcnt wait (global ops stay in flight).
#define BAR() asm volatile("s_waitcnt lgkmcnt(0)\n\ts_barrier" ::: "memory")

// DPP quad_perm lane swaps (xor 1 / xor 2 within each 4-lane quad).
__device__ __forceinline__ float qswap1(float x) {
  return __int_as_float(__builtin_amdgcn_mov_dpp(__float_as_int(x), 0xB1, 0xF, 0xF, true));
}
__device__ __forceinline__ float qswap2(float x) {
  return __int_as_float(__builtin_amdgcn_mov_dpp(__float_as_int(x), 0x4E, 0xF, 0xF, true));
}

// 32-element partial dot via 16 packed FMAs (4 independent chains).
__device__ __forceinline__ float dotpk16(const v2f av[16], const v2f tm[16]) {
  v2f a0 = av[0] * tm[0];
  v2f a1 = av[1] * tm[1];
  v2f a2 = av[2] * tm[2];
  v2f a3 = av[3] * tm[3];
  #pragma unroll
  for (int j = 4; j < 16; j += 4) {
    a0 = __builtin_elementwise_fma(av[j+0], tm[j+0], a0);
    a1 = __builtin_elementwise_fma(av[j+1], tm[j+1], a1);
    a2 = __builtin_elementwise_fma(av[j+2], tm[j+2], a2);
    a3 = __builtin_elementwise_fma(av[j+3], tm[j+3], a3);
  }
  v2f s = (a0 + a1) + (a2 + a3);
  return s.x + s.y;
}

__global__ __launch_bounds__(256, 1)
void soft_viterbi_kernel(const float* __restrict__ trans,
                         const float* __restrict__ emis,
                         const float* __restrict__ prior,
                         float* __restrict__ out) {
  const int b    = blockIdx.x;
  const int tid  = threadIdx.x;
  const int w    = tid >> 6;
  const int lane = tid & 63;
  const int k    = lane & 3;             // k-chunk within quad
  const int pid  = lane >> 2;            // state-pair id within wave (0..15)
  const int n0   = 32 * w + 2 * pid;     // first owned state (2 per lane)

  __shared__ __align__(16) float ubuf[2][NN];  // ping-pong alpha~ / q exchange
  __shared__ __align__(16) float sarr[TT];     // sarr[t] = 1/alpha~_t[0]
  __shared__ __align__(16) float red[NN];      // rowsum, then reduction scratch

  const float* embq = emis + (size_t)b * TT * NN + n0;  // float2 emission loads
  float* outb = out + (size_t)b * TT * NN;

  // ---- issue early global loads (prior, em[0..5]) ----
  float2 pr2 = *(const float2*)(prior + n0);
  float2 em0 = *(const float2*)(embq);
  float2 e1  = *(const float2*)(embq + 1 * NN);
  float2 e2  = *(const float2*)(embq + 2 * NN);
  float2 e3  = *(const float2*)(embq + 3 * NN);
  float2 e4  = *(const float2*)(embq + 4 * NN);
  float2 e5  = *(const float2*)(embq + 5 * NN);
  pr2.x = fmaxf(pr2.x, EPSC); pr2.y = fmaxf(pr2.y, EPSC);

  // ---- row sums of clipped transition ----
  if (tid < NN) {
    const float4* row = (const float4*)(trans + tid * NN);
    float s = 0.f;
    #pragma unroll 8
    for (int j = 0; j < NN / 4; ++j) {
      float4 v = row[j];
      s += fmaxf(v.x, EPSC) + fmaxf(v.y, EPSC) + fmaxf(v.z, EPSC) + fmaxf(v.w, EPSC);
    }
    red[tid] = s;
  }
  __syncthreads();

  // ---- forward fragment (pk-packed): tf2[s][2i+(c>>1)][c&1] = Tn[p][n0+s], p=4(k+4i)+c ----
  v2f tf2[2][16];
  #pragma unroll
  for (int i = 0; i < 8; ++i) {
    #pragma unroll
    for (int c = 0; c < 4; ++c) {
      const int p = 4 * (k + 4 * i) + c;
      const float2 tv = *(const float2*)(trans + p * NN + n0);
      const float rp = red[p];
      tf2[0][2*i + (c >> 1)][c & 1] = fmaxf(tv.x, EPSC) / rp;
      tf2[1][2*i + (c >> 1)][c & 1] = fmaxf(tv.y, EPSC) / rp;
    }
  }
  // ---- backward fragment: tb2[s][...] = Tn[n0+s][4(k+4i)+c] ----
  v2f tb2[2][16];
  #pragma unroll
  for (int s = 0; s < 2; ++s) {
    const float inv = 1.0f / red[n0 + s];
    const float4* rr = (const float4*)(trans + (n0 + s) * NN);
    #pragma unroll
    for (int i = 0; i < 8; ++i) {
      const float4 tv = rr[k + 4 * i];
      tb2[s][2*i+0][0] = fmaxf(tv.x, EPSC) * inv;
      tb2[s][2*i+0][1] = fmaxf(tv.y, EPSC) * inv;
      tb2[s][2*i+1][0] = fmaxf(tv.z, EPSC) * inv;
      tb2[s][2*i+1][1] = fmaxf(tv.w, EPSC) * inv;
    }
  }

  // ---- prior normalization ----
  float vv = (k == 0) ? (pr2.x + pr2.y) : 0.f;
  #pragma unroll
  for (int m = 1; m < 64; m <<= 1) vv += __shfl_xor(vv, m, 64);
  __syncthreads();                 // all tf/tb reads of red[] complete
  if (lane == 0) red[w] = vv;
  __syncthreads();
  const float psum = (red[0] + red[1]) + (red[2] + red[3]);

  // ---- u0 = alpha~_0 ----
  float an0 = (pr2.x / psum) * __expf(em0.x);
  float an1 = (pr2.y / psum) * __expf(em0.y);
  if (k == 0) {
    float2 a2v = make_float2(an0, an1);
    *(float2*)&ubuf[0][n0] = a2v;
    *(float2*)(outb + n0) = a2v;
  }
  float dc0 = __expf(e1.x), dc1 = __expf(e1.y);  // d_1
  // Emission ring: slot m&3 holds em[m]; entering step t slots hold em[t+1..t+4].
  float2 rg0 = e4, rg1 = e5, rg2 = e2, rg3 = e3;
  BAR();                           // publish ubuf[0]

  // ================= forward =================
  // Invariant entering step t: dc = d_t; slot (t+1)&3 holds em[t+1].
  // Body consumes slot (t+1)&3 (exp -> d_{t+1}) then refills it with
  // em[t+5] (same slot index; 4 steps of slack before consumption).
  auto fstep = [&](const float* rb, float* wb, int t, float2& slot) {
    const float r0 = rb[0];                       // broadcast read, lands early
    const float4* rb4 = (const float4*)rb;
    float4 a4[8];
    #pragma unroll
    for (int i = 0; i < 8; ++i) a4[i] = rb4[k + 4 * i];
    v2f av[16];
    #pragma unroll
    for (int i = 0; i < 8; ++i) {
      av[2*i+0][0] = a4[i].x; av[2*i+0][1] = a4[i].y;
      av[2*i+1][0] = a4[i].z; av[2*i+1][1] = a4[i].w;
    }
    float z0 = dotpk16(av, tf2[0]);
    float z1 = dotpk16(av, tf2[1]);
    z0 += qswap1(z0); z0 += qswap2(z0);
    z1 += qswap1(z1); z1 += qswap2(z1);
    const float rinv = 1.0f / r0;                 // off-chain (r0 early)
    an0 = (dc0 * rinv) * z0;
    an1 = (dc1 * rinv) * z1;
    dc0 = __expf(slot.x); dc1 = __expf(slot.y);   // d_{t+1}, off-chain
    const int tpre = (t + 5 < TT) ? (t + 5) : (TT - 1);
    slot = *(const float2*)(embq + (size_t)tpre * NN);  // em[t+5], slack 4 steps
    if (k == 0) {
      float2 a2v = make_float2(an0, an1);
      *(float2*)(wb + n0) = a2v;
      if (t < TT - 1) *(float2*)(outb + (size_t)t * NN + n0) = a2v;  // stash
    }
    if (tid == 0) sarr[t - 1] = rinv;             // r_{t-1}
    BAR();
  };

  fstep(ubuf[0], ubuf[1], 1, rg2);                // peel t=1,2,3
  fstep(ubuf[1], ubuf[0], 2, rg3);
  fstep(ubuf[0], ubuf[1], 3, rg0);
  for (int t = 4; t < TT; t += 4) {
    fstep(ubuf[1], ubuf[0], t + 0, rg1);
    fstep(ubuf[0], ubuf[1], t + 1, rg2);
    fstep(ubuf[1], ubuf[0], t + 2, rg3);
    fstep(ubuf[0], ubuf[1], t + 3, rg0);
  }
  const float dl0 = dc0, dl1 = dc1;               // = d_{T-1} (clamped ring)

  // ================= final softmax =================
  float v2 = (k == 0) ? (an0 + an1) : 0.f;
  #pragma unroll
  for (int m = 1; m < 64; m <<= 1) v2 += __shfl_xor(v2, m, 64);
  if (lane == 0) red[w] = v2;
  __syncthreads();
  const float total = (red[0] + red[1]) + (red[2] + red[3]);
  const float itot = 1.0f / total;
  float pc0 = an0 * itot, pc1 = an1 * itot;
  if (k == 0) *(float2*)(outb + (size_t)(TT - 1) * NN + n0) = make_float2(pc0, pc1);

  // One-time drain: forward alpha-stash stores must be visible before the
  // backward pass re-reads them (same-wave vmem ops are not address-ordered).
  asm volatile("s_waitcnt vmcnt(0)" ::: "memory");

  // ---- backward rings: slot m&3 holds em[m] / alpha~[m] ----
  float2 eb2 = *(const float2*)(embq + (size_t)510 * NN);  // em[510] -> slot 2
  float2 eb1 = *(const float2*)(embq + (size_t)509 * NN);  // em[509] -> slot 1
  float2 eb0 = *(const float2*)(embq + (size_t)508 * NN);  // em[508] -> slot 0
  float2 eb3 = *(const float2*)(embq + (size_t)507 * NN);  // em[507] -> slot 3
  float2 ac2 = *(const float2*)(outb + (size_t)510 * NN + n0);  // alpha~[510]
  float2 ac1 = *(const float2*)(outb + (size_t)509 * NN + n0);
  float2 ac0 = *(const float2*)(outb + (size_t)508 * NN + n0);
  float2 ac3 = *(const float2*)(outb + (size_t)507 * NN + n0);
  const float sl = sarr[TT - 2];
  float g0 = dl0 * sl / fmaxf(an0, TINY);         // g_{T-2}
  float g1 = dl1 * sl / fmaxf(an1, TINY);

  // ================= backward =================
  // Invariant entering step t: pc = p_{t+1}, g = g_t, em-slot t&3 = em[t],
  // ec-slot t&3 = alpha~_t. Body consumes both slots then refills with
  // index t-4 (same slot; 4 steps of slack).
  auto bstep = [&](float* xb, int t, float2& em_s, float2& ec_s) {
    if (k == 0) *(float2*)(xb + n0) = make_float2(pc0 * g0, pc1 * g1);
    const float sr = sarr[(t > 0) ? (t - 1) : 0];
    const float at0 = ec_s.x, at1 = ec_s.y;       // alpha~_t
    const float gn0 = __expf(em_s.x) * sr / fmaxf(at0, TINY);  // g_{t-1}
    const float gn1 = __expf(em_s.y) * sr / fmaxf(at1, TINY);
    const int tp4 = (t >= 4) ? (t - 4) : 0;
    em_s = *(const float2*)(embq + (size_t)tp4 * NN);        // em[t-4]
    ec_s = *(const float2*)(outb + (size_t)tp4 * NN + n0);   // alpha~[t-4]
    BAR();
    const float4* qb4 = (const float4*)xb;
    float4 a4[8];
    #pragma unroll
    for (int i = 0; i < 8; ++i) a4[i] = qb4[k + 4 * i];
    v2f av[16];
    #pragma unroll
    for (int i = 0; i < 8; ++i) {
      av[2*i+0][0] = a4[i].x; av[2*i+0][1] = a4[i].y;
      av[2*i+1][0] = a4[i].z; av[2*i+1][1] = a4[i].w;
    }
    float z0 = dotpk16(av, tb2[0]);
    float z1 = dotpk16(av, tb2[1]);
    z0 += qswap1(z0); z0 += qswap2(z0);
    z1 += qswap1(z1); z1 += qswap2(z1);
    pc0 = at0 * z0;                               // p_t
    pc1 = at1 * z1;
    if (k == 0) *(float2*)(outb + (size_t)t * NN + n0) = make_float2(pc0, pc1);
    g0 = gn0; g1 = gn1;
  };

  bstep(ubuf[0], 510, eb2, ac2);                  // peel t=510,509,508
  bstep(ubuf[1], 509, eb1, ac1);
  bstep(ubuf[0], 508, eb0, ac0);
  for (int t = 507; t >= 3; t -= 4) {
    bstep(ubuf[1], t - 0, eb3, ac3);
    bstep(ubuf[0], t - 1, eb2, ac2);
    bstep(ubuf[1], t - 2, eb1, ac1);
    bstep(ubuf[0], t - 3, eb0, ac0);
  }
}

extern "C" void kernel_launch(void* const* d_in, const int* in_sizes, int n_in,
                              void* d_out, int out_size, void* d_ws, size_t ws_size,
                              hipStream_t stream) {
  (void)in_sizes; (void)n_in; (void)d_ws; (void)ws_size; (void)out_size;
  const float* trans = (const float*)d_in[0];
  const float* emis  = (const float*)d_in[1];
  const float* prior = (const float*)d_in[2];
  float* out = (float*)d_out;
  soft_viterbi_kernel<<<dim3(BB), dim3(256), 0, stream>>>(trans, emis, prior, out);
}

// Round 6
// 398.891 us; speedup vs baseline: 1.4855x; 1.0535x over previous
//
#include <hip/hip_runtime.h>
#include <math.h>

// Soft-Viterbi structured decoding: B=32, T=512, N=128, fp32.
// Linear-space formulation, ONE barrier + ONE LDS round trip per step.
//
// Round-6: strip remaining VALU issue from the serial chain.
//  * v_rcp_f32 (1 instr) replaces exact fp32 division for ALL per-step
//    scale factors (forward rinv, backward 1/alpha). Safe: these are
//    normalizers — the algorithm is scale-invariant as long as the same
//    value is used consistently (rinv is stored to sarr and reused;
//    g uses the stored value), so rcp's ~1ulp error cancels.
//  * a4->av repack replaced by pointer cast (float4 and v2f[2] alias) —
//    guarantees zero v_mov repack instructions.
//  * Global loop addresses grouped as (uniform row pointer) + n0 so
//    per-step address math stays on the SALU pipe (co-issues with VALU).
// Everything else (layout, pk-FMA dot, DPP quad combine, LDS-only
// barrier, depth-4 rings) unchanged from round 5.

#define TT 512
#define BB 32
#define NN 128
#define EPSC 1e-10f
#define TINY 1e-33f

typedef float v2f __attribute__((ext_vector_type(2)));

// Fused LDS-drain + barrier. No vmcnt wait (global ops stay in flight).
#define BAR() asm volatile("s_waitcnt lgkmcnt(0)\n\ts_barrier" ::: "memory")

// Single-instruction v_rcp_f32 (~1ulp). Used only for scale factors where
// exactness is irrelevant (consistent-scale normalization).
__device__ __forceinline__ float rcp_fast(float x) {
  return __builtin_amdgcn_rcpf(x);
}

// DPP quad_perm lane swaps (xor 1 / xor 2 within each 4-lane quad).
__device__ __forceinline__ float qswap1(float x) {
  return __int_as_float(__builtin_amdgcn_mov_dpp(__float_as_int(x), 0xB1, 0xF, 0xF, true));
}
__device__ __forceinline__ float qswap2(float x) {
  return __int_as_float(__builtin_amdgcn_mov_dpp(__float_as_int(x), 0x4E, 0xF, 0xF, true));
}

// 32-element partial dot via 16 packed FMAs (4 independent chains).
__device__ __forceinline__ float dotpk16(const v2f* av, const v2f tm[16]) {
  v2f a0 = av[0] * tm[0];
  v2f a1 = av[1] * tm[1];
  v2f a2 = av[2] * tm[2];
  v2f a3 = av[3] * tm[3];
  #pragma unroll
  for (int j = 4; j < 16; j += 4) {
    a0 = __builtin_elementwise_fma(av[j+0], tm[j+0], a0);
    a1 = __builtin_elementwise_fma(av[j+1], tm[j+1], a1);
    a2 = __builtin_elementwise_fma(av[j+2], tm[j+2], a2);
    a3 = __builtin_elementwise_fma(av[j+3], tm[j+3], a3);
  }
  v2f s = (a0 + a1) + (a2 + a3);
  return s.x + s.y;
}

__global__ __launch_bounds__(256, 1)
void soft_viterbi_kernel(const float* __restrict__ trans,
                         const float* __restrict__ emis,
                         const float* __restrict__ prior,
                         float* __restrict__ out) {
  const int b    = blockIdx.x;
  const int tid  = threadIdx.x;
  const int w    = tid >> 6;
  const int lane = tid & 63;
  const int k    = lane & 3;             // k-chunk within quad
  const int pid  = lane >> 2;            // state-pair id within wave (0..15)
  const int n0   = 32 * w + 2 * pid;     // first owned state (2 per lane)

  __shared__ __align__(16) float ubuf[2][NN];  // ping-pong alpha~ / q exchange
  __shared__ __align__(16) float sarr[TT];     // sarr[t] = 1/alpha~_t[0]
  __shared__ __align__(16) float red[NN];      // rowsum, then reduction scratch

  const float* emB = emis + (size_t)b * TT * NN;  // uniform batch base
  float* outb      = out  + (size_t)b * TT * NN;  // uniform batch base

  // ---- issue early global loads (prior, em[0..5]) ----
  float2 pr2 = *(const float2*)(prior + n0);
  float2 em0 = *(const float2*)(emB + n0);
  float2 e1  = *(const float2*)(emB + 1 * NN + n0);
  float2 e2  = *(const float2*)(emB + 2 * NN + n0);
  float2 e3  = *(const float2*)(emB + 3 * NN + n0);
  float2 e4  = *(const float2*)(emB + 4 * NN + n0);
  float2 e5  = *(const float2*)(emB + 5 * NN + n0);
  pr2.x = fmaxf(pr2.x, EPSC); pr2.y = fmaxf(pr2.y, EPSC);

  // ---- row sums of clipped transition ----
  if (tid < NN) {
    const float4* row = (const float4*)(trans + tid * NN);
    float s = 0.f;
    #pragma unroll 8
    for (int j = 0; j < NN / 4; ++j) {
      float4 v = row[j];
      s += fmaxf(v.x, EPSC) + fmaxf(v.y, EPSC) + fmaxf(v.z, EPSC) + fmaxf(v.w, EPSC);
    }
    red[tid] = s;
  }
  __syncthreads();

  // ---- forward fragment (pk-packed): tf2[s][2i+(c>>1)][c&1] = Tn[p][n0+s], p=4(k+4i)+c ----
  v2f tf2[2][16];
  #pragma unroll
  for (int i = 0; i < 8; ++i) {
    #pragma unroll
    for (int c = 0; c < 4; ++c) {
      const int p = 4 * (k + 4 * i) + c;
      const float2 tv = *(const float2*)(trans + p * NN + n0);
      const float rp = red[p];
      tf2[0][2*i + (c >> 1)][c & 1] = fmaxf(tv.x, EPSC) / rp;
      tf2[1][2*i + (c >> 1)][c & 1] = fmaxf(tv.y, EPSC) / rp;
    }
  }
  // ---- backward fragment: tb2[s][...] = Tn[n0+s][4(k+4i)+c] ----
  v2f tb2[2][16];
  #pragma unroll
  for (int s = 0; s < 2; ++s) {
    const float inv = 1.0f / red[n0 + s];
    const float4* rr = (const float4*)(trans + (n0 + s) * NN);
    #pragma unroll
    for (int i = 0; i < 8; ++i) {
      const float4 tv = rr[k + 4 * i];
      tb2[s][2*i+0][0] = fmaxf(tv.x, EPSC) * inv;
      tb2[s][2*i+0][1] = fmaxf(tv.y, EPSC) * inv;
      tb2[s][2*i+1][0] = fmaxf(tv.z, EPSC) * inv;
      tb2[s][2*i+1][1] = fmaxf(tv.w, EPSC) * inv;
    }
  }

  // ---- prior normalization ----
  float vv = (k == 0) ? (pr2.x + pr2.y) : 0.f;
  #pragma unroll
  for (int m = 1; m < 64; m <<= 1) vv += __shfl_xor(vv, m, 64);
  __syncthreads();                 // all tf/tb reads of red[] complete
  if (lane == 0) red[w] = vv;
  __syncthreads();
  const float psum = (red[0] + red[1]) + (red[2] + red[3]);

  // ---- u0 = alpha~_0 ----
  float an0 = (pr2.x / psum) * __expf(em0.x);
  float an1 = (pr2.y / psum) * __expf(em0.y);
  if (k == 0) {
    float2 a2v = make_float2(an0, an1);
    *(float2*)&ubuf[0][n0] = a2v;
    *(float2*)(outb + n0) = a2v;
  }
  float dc0 = __expf(e1.x), dc1 = __expf(e1.y);  // d_1
  // Emission ring: slot m&3 holds em[m]; entering step t slots hold em[t+1..t+4].
  float2 rg0 = e4, rg1 = e5, rg2 = e2, rg3 = e3;
  BAR();                           // publish ubuf[0]

  // ================= forward =================
  // Invariant entering step t: dc = d_t; slot (t+1)&3 holds em[t+1].
  // Body consumes slot (t+1)&3 (exp -> d_{t+1}) then refills it with
  // em[t+5] (same slot index; 4 steps of slack before consumption).
  auto fstep = [&](const float* rb, float* wb, int t, float2& slot) {
    const float r0 = rb[0];                       // broadcast read, lands early
    const float4* rb4 = (const float4*)rb;
    float4 a4[8];
    #pragma unroll
    for (int i = 0; i < 8; ++i) a4[i] = rb4[k + 4 * i];
    const v2f* av = (const v2f*)a4;               // alias, no repack movs
    float z0 = dotpk16(av, tf2[0]);
    float z1 = dotpk16(av, tf2[1]);
    z0 += qswap1(z0); z0 += qswap2(z0);
    z1 += qswap1(z1); z1 += qswap2(z1);
    const float rinv = rcp_fast(r0);              // 1 instr; consistent scale
    an0 = (dc0 * rinv) * z0;
    an1 = (dc1 * rinv) * z1;
    dc0 = __expf(slot.x); dc1 = __expf(slot.y);   // d_{t+1}, off-chain
    const int tpre = (t + 5 < TT) ? (t + 5) : (TT - 1);
    const float* erow = emB + (size_t)tpre * NN;  // uniform row base (SALU)
    slot = *(const float2*)(erow + n0);           // em[t+5], slack 4 steps
    if (k == 0) {
      float2 a2v = make_float2(an0, an1);
      *(float2*)(wb + n0) = a2v;
      if (t < TT - 1) {
        float* orow = outb + (size_t)t * NN;      // uniform row base (SALU)
        *(float2*)(orow + n0) = a2v;              // stash
      }
    }
    if (tid == 0) sarr[t - 1] = rinv;             // r_{t-1}
    BAR();
  };

  fstep(ubuf[0], ubuf[1], 1, rg2);                // peel t=1,2,3
  fstep(ubuf[1], ubuf[0], 2, rg3);
  fstep(ubuf[0], ubuf[1], 3, rg0);
  for (int t = 4; t < TT; t += 4) {
    fstep(ubuf[1], ubuf[0], t + 0, rg1);
    fstep(ubuf[0], ubuf[1], t + 1, rg2);
    fstep(ubuf[1], ubuf[0], t + 2, rg3);
    fstep(ubuf[0], ubuf[1], t + 3, rg0);
  }
  const float dl0 = dc0, dl1 = dc1;               // = d_{T-1} (clamped ring)

  // ================= final softmax =================
  float v2 = (k == 0) ? (an0 + an1) : 0.f;
  #pragma unroll
  for (int m = 1; m < 64; m <<= 1) v2 += __shfl_xor(v2, m, 64);
  if (lane == 0) red[w] = v2;
  __syncthreads();
  const float total = (red[0] + red[1]) + (red[2] + red[3]);
  const float itot = 1.0f / total;
  float pc0 = an0 * itot, pc1 = an1 * itot;
  if (k == 0) *(float2*)(outb + (size_t)(TT - 1) * NN + n0) = make_float2(pc0, pc1);

  // One-time drain: forward alpha-stash stores must be visible before the
  // backward pass re-reads them (same-wave vmem ops are not address-ordered).
  asm volatile("s_waitcnt vmcnt(0)" ::: "memory");

  // ---- backward rings: slot m&3 holds em[m] / alpha~[m] ----
  float2 eb2 = *(const float2*)(emB  + (size_t)510 * NN + n0);  // em[510] -> slot 2
  float2 eb1 = *(const float2*)(emB  + (size_t)509 * NN + n0);
  float2 eb0 = *(const float2*)(emB  + (size_t)508 * NN + n0);
  float2 eb3 = *(const float2*)(emB  + (size_t)507 * NN + n0);
  float2 ac2 = *(const float2*)(outb + (size_t)510 * NN + n0);  // alpha~[510]
  float2 ac1 = *(const float2*)(outb + (size_t)509 * NN + n0);
  float2 ac0 = *(const float2*)(outb + (size_t)508 * NN + n0);
  float2 ac3 = *(const float2*)(outb + (size_t)507 * NN + n0);
  const float sl = sarr[TT - 2];
  float g0 = dl0 * sl * rcp_fast(fmaxf(an0, TINY));  // g_{T-2}
  float g1 = dl1 * sl * rcp_fast(fmaxf(an1, TINY));

  // ================= backward =================
  // Invariant entering step t: pc = p_{t+1}, g = g_t, em-slot t&3 = em[t],
  // ec-slot t&3 = alpha~_t. Body consumes both slots then refills with
  // index t-4 (same slot; 4 steps of slack).
  auto bstep = [&](float* xb, int t, float2& em_s, float2& ec_s) {
    if (k == 0) *(float2*)(xb + n0) = make_float2(pc0 * g0, pc1 * g1);
    const float sr = sarr[(t > 0) ? (t - 1) : 0];
    const float at0 = ec_s.x, at1 = ec_s.y;       // alpha~_t
    const float gn0 = __expf(em_s.x) * sr * rcp_fast(fmaxf(at0, TINY));  // g_{t-1}
    const float gn1 = __expf(em_s.y) * sr * rcp_fast(fmaxf(at1, TINY));
    const int tp4 = (t >= 4) ? (t - 4) : 0;
    const float* erow = emB  + (size_t)tp4 * NN;  // uniform row bases (SALU)
    const float* arow = outb + (size_t)tp4 * NN;
    em_s = *(const float2*)(erow + n0);           // em[t-4]
    ec_s = *(const float2*)(arow + n0);           // alpha~[t-4]
    BAR();
    const float4* qb4 = (const float4*)xb;
    float4 a4[8];
    #pragma unroll
    for (int i = 0; i < 8; ++i) a4[i] = qb4[k + 4 * i];
    const v2f* av = (const v2f*)a4;               // alias, no repack movs
    float z0 = dotpk16(av, tb2[0]);
    float z1 = dotpk16(av, tb2[1]);
    z0 += qswap1(z0); z0 += qswap2(z0);
    z1 += qswap1(z1); z1 += qswap2(z1);
    pc0 = at0 * z0;                               // p_t
    pc1 = at1 * z1;
    if (k == 0) {
      float* orow = outb + (size_t)t * NN;        // uniform row base (SALU)
      *(float2*)(orow + n0) = make_float2(pc0, pc1);
    }
    g0 = gn0; g1 = gn1;
  };

  bstep(ubuf[0], 510, eb2, ac2);                  // peel t=510,509,508
  bstep(ubuf[1], 509, eb1, ac1);
  bstep(ubuf[0], 508, eb0, ac0);
  for (int t = 507; t >= 3; t -= 4) {
    bstep(ubuf[1], t - 0, eb3, ac3);
    bstep(ubuf[0], t - 1, eb2, ac2);
    bstep(ubuf[1], t - 2, eb1, ac1);
    bstep(ubuf[0], t - 3, eb0, ac0);
  }
}

extern "C" void kernel_launch(void* const* d_in, const int* in_sizes, int n_in,
                              void* d_out, int out_size, void* d_ws, size_t ws_size,
                              hipStream_t stream) {
  (void)in_sizes; (void)n_in; (void)d_ws; (void)ws_size; (void)out_size;
  const float* trans = (const float*)d_in[0];
  const float* emis  = (const float*)d_in[1];
  const float* prior = (const float*)d_in[2];
  float* out = (float*)d_out;
  soft_viterbi_kernel<<<dim3(BB), dim3(256), 0, stream>>>(trans, emis, prior, out);
}